// Round 7
// baseline (9549.725 us; speedup 1.0000x reference)
//
#include <hip/hip_runtime.h>

// ---------------- problem constants ----------------
#define TT   2048
#define NB   16
#define HH   512
#define NSL  32            // WG slices per layer
#define HSL  16            // hidden units per slice
#define KW   128           // K-range per wave
#define Y_SZ (NB*TT*32)
#define RING 256
#define RM   255

typedef __attribute__((ext_vector_type(8))) short bf16x8;
typedef __attribute__((ext_vector_type(4))) float f32x4;
typedef __attribute__((ext_vector_type(4))) unsigned u32x4;
typedef unsigned long long ull;

// ---------------- workspace layout (bytes) ----------------
#define OFF_XCCV 0u
#define OFF_MODE 256u
#define OFF_PROG 512u
#define OFF_F1L  4096u
#define FLB      (4u*RING*32u*4u)
#define OFF_F1X  (OFF_F1L + FLB)
#define OFF_F2L  (OFF_F1X + FLB)
#define OFF_F2X  (OFF_F2L + FLB)
#define OFF_ZEND (OFF_F2X + FLB)
#define RSLOT    ((size_t)NB*HH)
#define RB       ((size_t)RING*RSLOT*2)
#define OFF_H1LH ((size_t)(1u<<20))
#define OFF_H1LL (OFF_H1LH + RB)
#define OFF_H1XH (OFF_H1LL + RB)
#define OFF_H1XL (OFF_H1XH + RB)
#define OFF_H2LH (OFF_H1XL + RB)
#define OFF_H2LL (OFF_H2LH + RB)
#define OFF_H2XH (OFF_H2LL + RB)
#define OFF_H2XL (OFF_H2XH + RB)
#define FB       ((size_t)TT*RSLOT*2)
#define OFF_H2FH (OFF_H2XL + RB)
#define OFF_H2FL (OFF_H2FH + FB)
#define WS_NEED  (OFF_H2FL + FB)

__device__ __forceinline__ unsigned short f2bf(float x){
  unsigned u = __float_as_uint(x);
  return (unsigned short)((u + 0x7FFFu + ((u >> 16) & 1u)) >> 16);
}
__device__ __forceinline__ float bf2f(unsigned short b){
  return __uint_as_float(((unsigned)b) << 16);
}
__device__ __forceinline__ float sigm(float v){ return 1.0f / (1.0f + __expf(-v)); }
__device__ __forceinline__ float tanh_f(float v){
  float a = fabsf(v);
  float e = __expf(-2.0f * a);
  float t = (1.0f - e) / (1.0f + e);
  return v < 0.0f ? -t : t;
}
__device__ __forceinline__ void split8(const float* __restrict__ p, bf16x8& hi, bf16x8& lo){
#pragma unroll
  for (int j = 0; j < 8; ++j){
    float w = p[j];
    unsigned short h = f2bf(w);
    hi[j] = (short)h;
    lo[j] = (short)f2bf(w - bf2f(h));
  }
}
__device__ __forceinline__ bf16x8 mk(ull a, ull b){
  union { ull u[2]; bf16x8 v; } r; r.u[0] = a; r.u[1] = b; return r.v;
}
__device__ __forceinline__ bf16x8 asfrag(u32x4 v){
  union { u32x4 u; bf16x8 b; } r; r.u = v; return r.b;
}
// ---- LIC (agent-scope) primitives ----
__device__ __forceinline__ ull ld64_lic(const ull* p){
  return __hip_atomic_load(p, __ATOMIC_RELAXED, __HIP_MEMORY_SCOPE_AGENT);
}
__device__ __forceinline__ unsigned ld32_lic(const unsigned* p){
  return __hip_atomic_load(p, __ATOMIC_RELAXED, __HIP_MEMORY_SCOPE_AGENT);
}
__device__ __forceinline__ void st64_lic(ull* p, ull v){
  __hip_atomic_store(p, v, __ATOMIC_RELAXED, __HIP_MEMORY_SCOPE_AGENT);
}
__device__ __forceinline__ void st32_lic(unsigned* p, unsigned v){
  __hip_atomic_store(p, v, __ATOMIC_RELAXED, __HIP_MEMORY_SCOPE_AGENT);
}
__device__ __forceinline__ bf16x8 ld_frag_lic(const unsigned short* p){
  return mk(ld64_lic((const ull*)p), ld64_lic((const ull*)p + 1));
}
// ---- XCD-local primitives: sc0 (coherent, L1-bypass) L2-served loads ----
__device__ __forceinline__ unsigned ld32_l2(const unsigned* p){
  unsigned r;
  asm volatile("global_load_dword %0, %1, off sc0\n\t"
               "s_waitcnt vmcnt(0)"
               : "=&v"(r) : "v"(p) : "memory");
  return r;
}
__device__ __forceinline__ void ld8_l2(const void* ph, const void* pl, u32x4* r){
  asm volatile(
    "global_load_dwordx4 %0, %8, off sc0\n\t"
    "global_load_dwordx4 %1, %8, off offset:64 sc0\n\t"
    "global_load_dwordx4 %2, %8, off offset:128 sc0\n\t"
    "global_load_dwordx4 %3, %8, off offset:192 sc0\n\t"
    "global_load_dwordx4 %4, %9, off sc0\n\t"
    "global_load_dwordx4 %5, %9, off offset:64 sc0\n\t"
    "global_load_dwordx4 %6, %9, off offset:128 sc0\n\t"
    "global_load_dwordx4 %7, %9, off offset:192 sc0\n\t"
    "s_waitcnt vmcnt(0)"
    : "=&v"(r[0]),"=&v"(r[1]),"=&v"(r[2]),"=&v"(r[3]),
      "=&v"(r[4]),"=&v"(r[5]),"=&v"(r[6]),"=&v"(r[7])
    : "v"(ph), "v"(pl) : "memory");
}
// batched LIC loads, FULLY WAITED inside the block
__device__ __forceinline__ void ld8_lic(const void* ph, const void* pl, u32x4* r){
  asm volatile(
    "global_load_dwordx4 %0, %8, off sc0 sc1\n\t"
    "global_load_dwordx4 %1, %8, off offset:64 sc0 sc1\n\t"
    "global_load_dwordx4 %2, %8, off offset:128 sc0 sc1\n\t"
    "global_load_dwordx4 %3, %8, off offset:192 sc0 sc1\n\t"
    "global_load_dwordx4 %4, %9, off sc0 sc1\n\t"
    "global_load_dwordx4 %5, %9, off offset:64 sc0 sc1\n\t"
    "global_load_dwordx4 %6, %9, off offset:128 sc0 sc1\n\t"
    "global_load_dwordx4 %7, %9, off offset:192 sc0 sc1\n\t"
    "s_waitcnt vmcnt(0)"
    : "=&v"(r[0]),"=&v"(r[1]),"=&v"(r[2]),"=&v"(r[3]),
      "=&v"(r[4]),"=&v"(r[5]),"=&v"(r[6]),"=&v"(r[7])
    : "v"(ph), "v"(pl) : "memory");
}
// batched LIC loads, ISSUE ONLY (caller merges the vmcnt(0) with store drain)
__device__ __forceinline__ void ld8_lic_issue(const void* ph, const void* pl, u32x4* r){
  asm volatile(
    "global_load_dwordx4 %0, %8, off sc0 sc1\n\t"
    "global_load_dwordx4 %1, %8, off offset:64 sc0 sc1\n\t"
    "global_load_dwordx4 %2, %8, off offset:128 sc0 sc1\n\t"
    "global_load_dwordx4 %3, %8, off offset:192 sc0 sc1\n\t"
    "global_load_dwordx4 %4, %9, off sc0 sc1\n\t"
    "global_load_dwordx4 %5, %9, off offset:64 sc0 sc1\n\t"
    "global_load_dwordx4 %6, %9, off offset:128 sc0 sc1\n\t"
    "global_load_dwordx4 %7, %9, off offset:192 sc0 sc1"
    : "=&v"(r[0]),"=&v"(r[1]),"=&v"(r[2]),"=&v"(r[3]),
      "=&v"(r[4]),"=&v"(r[5]),"=&v"(r[6]),"=&v"(r[7])
    : "v"(ph), "v"(pl) : "memory");
}
__device__ __forceinline__ void st64_pl(void* p, ull v){
  asm volatile("global_store_dwordx2 %0, %1, off" :: "v"(p), "v"(v) : "memory");
}
__device__ __forceinline__ void st32_pl(unsigned* p, unsigned v){
  asm volatile("global_store_dword %0, %1, off" :: "v"(p), "v"(v) : "memory");
}

// ---- waits (r13: OCTET scope) ----
// Wave wv's MFMA consumes h columns kwb..kwb+127, produced by exactly
// slices wv*8..wv*8+7 (column j comes from slice j/16). So each wait only
// needs 8 producer flags (base = wv*8), not 32: stall on max-of-8 not
// max-of-32, and 4x fewer flag loads per poll round. Publication side is
// untouched (flags still written for all 4 wave-rows x 32 slices).
// hybrid: 1 = local ok, 0 = use LIC path
__device__ __forceinline__ int wait_hy8(const unsigned* bL, const unsigned* bX,
                                        unsigned expect, int lane, int base, int lmode, long& bud){
  if (!lmode){
    bool ok = (lane >= 8);
    while (__ballot(!ok) != 0ULL){
      if (!ok) ok = (ld32_lic(bX + base + lane) >= expect);
      if (--bud < 0) return 0;
    }
    return 0;
  }
  bool okL = (lane >= 8);
  int k = 0;
  while (true){
    if (__ballot(!okL) == 0ULL) return 1;
    if (!okL) okL = (ld32_l2(bL + base + lane) >= expect);
    if ((++k & 15) == 0){
      bool okX = (lane >= 8);
      if (!okX) okX = (ld32_lic(bX + base + lane) >= expect);
      if (__ballot(!okX) == 0ULL){
        if (!okL) okL = (ld32_l2(bL + base + lane) >= expect);
        return (__ballot(!okL) == 0ULL) ? 1 : 0;
      }
    }
    if (--bud < 0) return 0;
  }
}
// LIC-only value wait, octet scope
__device__ __forceinline__ void wait_lic8(const unsigned* bX, unsigned expect, int lane, int base, long& bud){
  bool ok = (lane >= 8);
  while (__ballot(!ok) != 0ULL){
    if (!ok) ok = (ld32_lic(bX + base + lane) >= expect);
    if (--bud < 0) return;
  }
}

// =====================================================================
// Persistent 2-layer LSTM — r13: r11 (passing, 9450 us) + ONE isolated
// change: octet-scope waits (poll 8 producer flags, the wave's K-range,
// instead of 32). No publication/ordering/barrier changes.
// Post-mortem context: r12's vote/lean rewrite corrupted (same signature
// as the r8-r10 remap failures despite the original role map) — multi-
// part blind protocol changes are off the table; single isolated deltas
// on the passing baseline only.
// =====================================================================
__global__ __launch_bounds__(256, 1) void lstm_persist(
    const float* __restrict__ x,
    const float* __restrict__ w_ih0, const float* __restrict__ w_hh0,
    const float* __restrict__ b_ih0, const float* __restrict__ b_hh0,
    const float* __restrict__ w_ih1, const float* __restrict__ w_hh1,
    const float* __restrict__ b_ih1, const float* __restrict__ b_hh1,
    float* __restrict__ out, unsigned char* __restrict__ ws)
{
  unsigned* XCCV = (unsigned*)(ws + OFF_XCCV);
  unsigned* MODE = (unsigned*)(ws + OFF_MODE);
  unsigned* PROG = (unsigned*)(ws + OFF_PROG);
  unsigned* F1L  = (unsigned*)(ws + OFF_F1L);
  unsigned* F1X  = (unsigned*)(ws + OFF_F1X);
  unsigned* F2L  = (unsigned*)(ws + OFF_F2L);
  unsigned* F2X  = (unsigned*)(ws + OFF_F2X);
  unsigned short* H1Lh = (unsigned short*)(ws + OFF_H1LH);
  unsigned short* H1Ll = (unsigned short*)(ws + OFF_H1LL);
  unsigned short* H1Xh = (unsigned short*)(ws + OFF_H1XH);
  unsigned short* H1Xl = (unsigned short*)(ws + OFF_H1XL);
  unsigned short* H2Lh = (unsigned short*)(ws + OFF_H2LH);
  unsigned short* H2Ll = (unsigned short*)(ws + OFF_H2LL);
  unsigned short* H2Xh = (unsigned short*)(ws + OFF_H2XH);
  unsigned short* H2Xl = (unsigned short*)(ws + OFF_H2XL);
  unsigned short* H2Fh = (unsigned short*)(ws + OFF_H2FH);
  unsigned short* H2Fl = (unsigned short*)(ws + OFF_H2FL);

  const int tid  = threadIdx.x;
  const int lane = tid & 63;
  const int wv   = tid >> 6;
  const int m16  = lane & 15;
  const int quad = lane >> 4;

  const int bid = blockIdx.x;
  const int xs  = bid & 7;
  const int pos = bid >> 3;
  if (xs >= 2 || pos >= NSL) return;
  const int layer = xs;
  const int sl    = pos;
  const int role  = layer * NSL + sl;
  const int j0    = sl * HSL;
  const int kwb   = wv * KW;
  const int fb8   = wv * 8;            // octet flag base (this wave's producers)

  long bud = 3000000;

  // ---- placement verification (r6) ----
  if (tid == 0){
    unsigned xcc = 0xDEAD;
    asm volatile("s_getreg_b32 %0, hwreg(HW_REG_XCC_ID)" : "=s"(xcc));
    st32_lic(XCCV + role, (xcc & 255u) | 0x100u);
  }
  __syncthreads();
  if (bid == 0 && wv == 0){
    bool got = false; unsigned v = 0;
    long b2 = 2000000;
    while (true){
      if (!got){ v = ld32_lic(XCCV + lane); got = (v & 0x100u) != 0u; }
      if (__ballot(!got) == 0ULL) break;
      if (--b2 < 0) break;
    }
    unsigned v0  = (unsigned)__shfl((int)v, 0, 64);
    unsigned v32 = (unsigned)__shfl((int)v, 32, 64);
    bool ok = got && ((lane < 32) ? (v == v0) : (v == v32));
    unsigned mode = (__ballot(!ok) == 0ULL) ? 1u : 0u;
    if (lane == 0) st32_lic(MODE, mode | 0x100u);
  }
  __shared__ unsigned s_mode;
  if (tid == 0){
    unsigned m = 0; long b3 = 2000000;
    do { m = ld32_lic(MODE); } while (!(m & 0x100u) && --b3 > 0);
    s_mode = m;
  }
  __syncthreads();
  int lmode = ((s_mode & 0x100u) && (s_mode & 1u)) ? 1 : 0;

  const float* Wh  = layer ? w_hh1 : w_hh0;
  const float* biL = layer ? b_ih1 : b_ih0;
  const float* bhL = layer ? b_hh1 : b_hh0;

  bf16x8 Bh_hi[4][4], Bh_lo[4][4];
#pragma unroll
  for (int g = 0; g < 4; ++g)
#pragma unroll
    for (int c = 0; c < 4; ++c){
      int row = g*HH + j0 + m16;
      int k0  = kwb + c*32 + quad*8;
      split8(Wh + (size_t)row*HH + k0, Bh_hi[g][c], Bh_lo[g][c]);
    }
  bf16x8 Bi_hi[4][4], Bi_lo[4][4];
  if (layer){
#pragma unroll
    for (int g = 0; g < 4; ++g)
#pragma unroll
      for (int c = 0; c < 4; ++c){
        int row = g*HH + j0 + m16;
        int k0  = kwb + c*32 + quad*8;
        split8(w_ih1 + (size_t)row*HH + k0, Bi_hi[g][c], Bi_lo[g][c]);
      }
  } else if (wv == 0){
#pragma unroll
    for (int g = 0; g < 4; ++g){
      int row = g*HH + j0 + m16;
      split8(w_ih0 + (size_t)row*32 + quad*8, Bi_hi[g][0], Bi_lo[g][0]);
    }
  }

  const int eb = tid >> 4;
  const int ej = tid & 15;
  float bias[4];
#pragma unroll
  for (int g = 0; g < 4; ++g){
    int r = g*HH + j0 + ej;
    bias[g] = biL[r] + bhL[r];
  }

  float cst = 0.0f;
  __shared__ float P[4][4][16][16];   // unpadded: reads 2 lanes/bank = free
  unsigned minp = 0;
  unsigned f1seen = 0;                // highest verified F1X value (layer1 tail batching)

  // ---- layer1 preamble: input matmul for step 0 (h1(0) = H1X slot 1) ----
  f32x4 accIn[4];
#pragma unroll
  for (int g = 0; g < 4; ++g) accIn[g] = f32x4{0.f, 0.f, 0.f, 0.f};
  if (layer){
    wait_lic8(F1X + ((size_t)wv*RING + 1)*32, 1u, lane, fb8, bud);
    f1seen = 1u;
    const size_t ib = ((size_t)1*NB + m16)*HH + kwb + quad*8;
    u32x4 r[8];
    ld8_lic(H1Xh + ib, H1Xl + ib, r);
#pragma unroll
    for (int c = 0; c < 4; ++c){
      bf16x8 ah = asfrag(r[c]);
      bf16x8 al = asfrag(r[4+c]);
#pragma unroll
      for (int g = 0; g < 4; ++g){
        accIn[g] = __builtin_amdgcn_mfma_f32_16x16x32_bf16(ah, Bi_hi[g][c], accIn[g], 0, 0, 0);
        accIn[g] = __builtin_amdgcn_mfma_f32_16x16x32_bf16(al, Bi_hi[g][c], accIn[g], 0, 0, 0);
        accIn[g] = __builtin_amdgcn_mfma_f32_16x16x32_bf16(ah, Bi_lo[g][c], accIn[g], 0, 0, 0);
      }
    }
  }

  for (int t = 0; t < TT; ++t){
    const unsigned srec = (unsigned)t & RM;
    const unsigned spub = (unsigned)(t+1) & RM;
    f32x4 acc[4];

    if (layer == 0){
#pragma unroll
      for (int g = 0; g < 4; ++g) acc[g] = f32x4{0.f, 0.f, 0.f, 0.f};
      if (wv == 0){                        // x-term overlaps waits
        const float* xp = x + ((size_t)m16*TT + t)*32 + quad*8;
        bf16x8 ah, al;
#pragma unroll
        for (int j = 0; j < 8; ++j){
          float v = xp[j];
          unsigned short h = f2bf(v);
          ah[j] = (short)h;
          al[j] = (short)f2bf(v - bf2f(h));
        }
#pragma unroll
        for (int g = 0; g < 4; ++g){
          acc[g] = __builtin_amdgcn_mfma_f32_16x16x32_bf16(ah, Bi_hi[g][0], acc[g], 0, 0, 0);
          acc[g] = __builtin_amdgcn_mfma_f32_16x16x32_bf16(al, Bi_hi[g][0], acc[g], 0, 0, 0);
          acc[g] = __builtin_amdgcn_mfma_f32_16x16x32_bf16(ah, Bi_lo[g][0], acc[g], 0, 0, 0);
        }
      }
      while ((long)(t+1) - (long)minp > 248L){          // ring backpressure
        unsigned v = (lane < 32) ? ld32_lic(PROG + lane) : 0xFFFFFFFFu;
        unsigned m = v;
#pragma unroll
        for (int o = 1; o < 32; o <<= 1){
          unsigned ov = (unsigned)__shfl_xor((int)m, o, 32);
          m = m < ov ? m : ov;
        }
        minp = (unsigned)__shfl((int)m, 0, 64);
        if (--bud < 0) break;
      }
      int got = lmode;
      if (t > 0){
        got = wait_hy8(F1L + ((size_t)wv*RING + srec)*32,
                       F1X + ((size_t)wv*RING + srec)*32, (unsigned)t, lane, fb8, lmode, bud);
        if (!got) lmode = 0;
      }
      const size_t rb = ((size_t)srec*NB + m16)*HH + kwb + quad*8;
      u32x4 r[8];
      if (got) ld8_l2(H1Lh + rb, H1Ll + rb, r);
      else {
#pragma unroll
        for (int c = 0; c < 4; ++c){
          r[c]   = (u32x4)__builtin_bit_cast(u32x4, ld_frag_lic(H1Xh + rb + c*32));
          r[4+c] = (u32x4)__builtin_bit_cast(u32x4, ld_frag_lic(H1Xl + rb + c*32));
        }
      }
#pragma unroll
      for (int c = 0; c < 4; ++c){
        bf16x8 ah = asfrag(r[c]);
        bf16x8 al = asfrag(r[4+c]);
#pragma unroll
        for (int g = 0; g < 4; ++g){
          acc[g] = __builtin_amdgcn_mfma_f32_16x16x32_bf16(ah, Bh_hi[g][c], acc[g], 0, 0, 0);
          acc[g] = __builtin_amdgcn_mfma_f32_16x16x32_bf16(al, Bh_hi[g][c], acc[g], 0, 0, 0);
          acc[g] = __builtin_amdgcn_mfma_f32_16x16x32_bf16(ah, Bh_lo[g][c], acc[g], 0, 0, 0);
        }
      }
    } else {
      // acc starts from the pipelined input matmul (h1(t) @ W_ih1^T)
#pragma unroll
      for (int g = 0; g < 4; ++g) acc[g] = accIn[g];
      int got = lmode;
      if (t > 0){
        got = wait_hy8(F2L + ((size_t)wv*RING + srec)*32,
                       F2X + ((size_t)wv*RING + srec)*32, (unsigned)t, lane, fb8, lmode, bud);
        if (!got) lmode = 0;
      }
      const size_t rb = ((size_t)srec*NB + m16)*HH + kwb + quad*8;
      u32x4 r[8];
      if (got) ld8_l2(H2Lh + rb, H2Ll + rb, r);
      else {
#pragma unroll
        for (int c = 0; c < 4; ++c){
          r[c]   = (u32x4)__builtin_bit_cast(u32x4, ld_frag_lic(H2Xh + rb + c*32));
          r[4+c] = (u32x4)__builtin_bit_cast(u32x4, ld_frag_lic(H2Xl + rb + c*32));
        }
      }
#pragma unroll
      for (int c = 0; c < 4; ++c){
        bf16x8 ah = asfrag(r[c]);
        bf16x8 al = asfrag(r[4+c]);
#pragma unroll
        for (int g = 0; g < 4; ++g){
          acc[g] = __builtin_amdgcn_mfma_f32_16x16x32_bf16(ah, Bh_hi[g][c], acc[g], 0, 0, 0);
          acc[g] = __builtin_amdgcn_mfma_f32_16x16x32_bf16(al, Bh_hi[g][c], acc[g], 0, 0, 0);
          acc[g] = __builtin_amdgcn_mfma_f32_16x16x32_bf16(ah, Bh_lo[g][c], acc[g], 0, 0, 0);
        }
      }
    }

    // ---- K-reduction via LDS ----
#pragma unroll
    for (int g = 0; g < 4; ++g)
#pragma unroll
      for (int r = 0; r < 4; ++r)
        P[wv][g][quad*4 + r][m16] = acc[g][r];
    __syncthreads();                                   // barrier A

    float G[4];
#pragma unroll
    for (int g = 0; g < 4; ++g)
      G[g] = P[0][g][eb][ej] + P[1][g][eb][ej] + P[2][g][eb][ej] + P[3][g][eb][ej] + bias[g];

    float gi = sigm(G[0]);
    float gf = sigm(G[1]);
    float gc = tanh_f(G[2]);
    float go = sigm(G[3]);
    cst = gf*cst + gi*gc;
    float h = go * tanh_f(cst);

    if (t == TT-1){
      size_t o = (size_t)layer*NB*HH + (size_t)eb*HH + (j0 + ej);
      out[Y_SZ + o] = h;
      out[Y_SZ + 2*NB*HH + o] = cst;
    }

    // ---- dual publish: plain (XCD L2) first, agent (LIC) second ----
    unsigned short hhi = f2bf(h);
    unsigned short hlo = f2bf(h - bf2f(hhi));
    ull h1s = (ull)(unsigned short)__shfl_down((int)hhi, 1, 64);
    ull h2s = (ull)(unsigned short)__shfl_down((int)hhi, 2, 64);
    ull h3s = (ull)(unsigned short)__shfl_down((int)hhi, 3, 64);
    ull l1s = (ull)(unsigned short)__shfl_down((int)hlo, 1, 64);
    ull l2s = (ull)(unsigned short)__shfl_down((int)hlo, 2, 64);
    ull l3s = (ull)(unsigned short)__shfl_down((int)hlo, 3, 64);
    if ((ej & 3) == 0){
      ull vh = (ull)hhi | (h1s << 16) | (h2s << 32) | (h3s << 48);
      ull vl = (ull)hlo | (l1s << 16) | (l2s << 32) | (l3s << 48);
      size_t pr = (((size_t)spub*NB + eb)*HH + (unsigned)(j0 + ej)) >> 2;
      if (layer == 0){
        st64_pl((ull*)H1Lh + pr, vh);
        st64_pl((ull*)H1Ll + pr, vl);
        st64_lic((ull*)H1Xh + pr, vh);
        st64_lic((ull*)H1Xl + pr, vl);
      } else {
        size_t pf_ = (((size_t)t*NB + eb)*HH + (unsigned)(j0 + ej)) >> 2;
        st64_pl((ull*)H2Lh + pr, vh);
        st64_pl((ull*)H2Ll + pr, vl);
        st64_pl((ull*)H2Fh + pf_, vh);
        st64_pl((ull*)H2Fl + pf_, vl);
        st64_lic((ull*)H2Xh + pr, vh);
        st64_lic((ull*)H2Xl + pr, vl);
      }
    }

    if (layer == 0){
      // certify ONLY the plain H1L stores (in-order vmcnt retire: they are
      // the oldest), publish L flags, then pay the LIC ack off the
      // consumers' detect path.
      asm volatile("s_waitcnt vmcnt(2) lgkmcnt(0)" ::: "memory");
      __builtin_amdgcn_s_barrier();                    // barrier B (raw)
      if (tid == 0){
        unsigned val = (unsigned)(t+1);
#pragma unroll
        for (int r2 = 0; r2 < 4; ++r2)
          st32_pl(F1L + ((size_t)r2*RING + spub)*32 + sl, val);
      }
      asm volatile("s_waitcnt vmcnt(0)" ::: "memory"); // certify agent stores
      __builtin_amdgcn_s_barrier();                    // barrier C (raw)
      if (tid == 0){
        unsigned val = (unsigned)(t+1);
#pragma unroll
        for (int r2 = 0; r2 < 4; ++r2)
          st32_lic(F1X + ((size_t)r2*RING + spub)*32 + sl, val);
      }
    } else {
      // certify ONLY the plain H2L stores (oldest 2 of the 6; at t==TT-1
      // the out[] stores precede and vmcnt(4) still retires past H2L).
      asm volatile("s_waitcnt vmcnt(4) lgkmcnt(0)" ::: "memory");
      __builtin_amdgcn_s_barrier();                    // barrier B (raw)
      if (tid == 0){
        unsigned val = (unsigned)(t+1);
#pragma unroll
        for (int r2 = 0; r2 < 4; ++r2)
          st32_pl(F2L + ((size_t)r2*RING + spub)*32 + sl, val);
      }
      if (t + 1 < TT){
        // ---- tail: h1 prefetch overlapped with the LIC store drain ----
        if (f1seen < (unsigned)(t+2)){                 // batched flag check
          unsigned tgt = (unsigned)(t + 17);
          if (tgt > (unsigned)TT) tgt = (unsigned)TT;
          wait_lic8(F1X + ((size_t)wv*RING + (tgt & RM))*32, tgt, lane, fb8, bud);
          f1seen = tgt;
        }
        const unsigned nslot = (unsigned)(t+2) & RM;
        const size_t nb_ = ((size_t)nslot*NB + m16)*HH + kwb + quad*8;
        u32x4 rr[8];
        ld8_lic_issue(H1Xh + nb_, H1Xl + nb_, rr);
        // one drain window: H2F/H2X store acks + the 8 LIC loads together
        asm volatile("s_waitcnt vmcnt(0)" ::: "memory");
        __builtin_amdgcn_sched_barrier(0);
        __builtin_amdgcn_s_barrier();                  // barrier C (raw)
        if (tid == 0){
          unsigned val = (unsigned)(t+1);
#pragma unroll
          for (int r2 = 0; r2 < 4; ++r2)
            st32_lic(F2X + ((size_t)r2*RING + spub)*32 + sl, val);
          st32_lic(PROG + sl, val);
        }
#pragma unroll
        for (int g = 0; g < 4; ++g) accIn[g] = f32x4{0.f, 0.f, 0.f, 0.f};
#pragma unroll
        for (int c = 0; c < 4; ++c){
          bf16x8 ah = asfrag(rr[c]);
          bf16x8 al = asfrag(rr[4+c]);
#pragma unroll
          for (int g = 0; g < 4; ++g){
            accIn[g] = __builtin_amdgcn_mfma_f32_16x16x32_bf16(ah, Bi_hi[g][c], accIn[g], 0, 0, 0);
            accIn[g] = __builtin_amdgcn_mfma_f32_16x16x32_bf16(al, Bi_hi[g][c], accIn[g], 0, 0, 0);
            accIn[g] = __builtin_amdgcn_mfma_f32_16x16x32_bf16(ah, Bi_lo[g][c], accIn[g], 0, 0, 0);
          }
        }
      }
      // t == TT-1: F2X(TT)/PROG(TT) have no consumer — skip; kernel-end
      // completion drains the remaining stores.
    }
  }
}

// =====================================================================
// y = h2 @ w_out^T + b_out   (parallel epilogue, one block per timestep)
// =====================================================================
__global__ __launch_bounds__(256, 1) void y_proj(
    const unsigned short* __restrict__ Hhi2, const unsigned short* __restrict__ Hlo2,
    const float* __restrict__ w_out, const float* __restrict__ b_out,
    float* __restrict__ out)
{
  __shared__ float hsh[NB][HH + 1];
  __shared__ float wsh[32][HH + 1];
  const int tid = threadIdx.x;
  const int t = blockIdx.x;

  for (int i = tid; i < 32*HH; i += 256){
    int o = i >> 9, k = i & (HH-1);
    wsh[o][k] = w_out[i];
  }
  for (int i = tid; i < NB*HH; i += 256){
    int b = i >> 9, k = i & (HH-1);
    size_t off = ((size_t)t*NB + b)*HH + k;
    hsh[b][k] = bf2f(Hhi2[off]) + bf2f(Hlo2[off]);
  }
  __syncthreads();

  const int o = tid & 31, bg = tid >> 5;
  float a0 = 0.f, a1 = 0.f;
  for (int k = 0; k < HH; ++k){
    float w = wsh[o][k];
    a0 += w * hsh[bg][k];
    a1 += w * hsh[bg + 8][k];
  }
  float bo = b_out[o];
  out[((size_t)bg*TT + t)*32 + o] = a0 + bo;
  out[((size_t)(bg+8)*TT + t)*32 + o] = a1 + bo;
}

extern "C" void kernel_launch(void* const* d_in, const int* in_sizes, int n_in,
                              void* d_out, int out_size, void* d_ws, size_t ws_size,
                              hipStream_t stream)
{
  (void)in_sizes; (void)n_in; (void)out_size;
  const float* x     = (const float*)d_in[0];
  const float* w_ih0 = (const float*)d_in[1];
  const float* w_hh0 = (const float*)d_in[2];
  const float* b_ih0 = (const float*)d_in[3];
  const float* b_hh0 = (const float*)d_in[4];
  const float* w_ih1 = (const float*)d_in[5];
  const float* w_hh1 = (const float*)d_in[6];
  const float* b_ih1 = (const float*)d_in[7];
  const float* b_hh1 = (const float*)d_in[8];
  const float* w_out = (const float*)d_in[9];
  const float* b_out = (const float*)d_in[10];
  float* out = (float*)d_out;
  unsigned char* ws = (unsigned char*)d_ws;

  if (ws_size < WS_NEED) return;

  hipMemsetAsync(ws, 0, OFF_ZEND, stream);
  hipMemsetAsync(ws + OFF_H1LH, 0, RSLOT*2, stream);
  hipMemsetAsync(ws + OFF_H1LL, 0, RSLOT*2, stream);
  hipMemsetAsync(ws + OFF_H1XH, 0, RSLOT*2, stream);
  hipMemsetAsync(ws + OFF_H1XL, 0, RSLOT*2, stream);
  hipMemsetAsync(ws + OFF_H2LH, 0, RSLOT*2, stream);
  hipMemsetAsync(ws + OFF_H2LL, 0, RSLOT*2, stream);
  hipMemsetAsync(ws + OFF_H2XH, 0, RSLOT*2, stream);
  hipMemsetAsync(ws + OFF_H2XL, 0, RSLOT*2, stream);

  lstm_persist<<<dim3(512), dim3(256), 0, stream>>>(
      x, w_ih0, w_hh0, b_ih0, b_hh0, w_ih1, w_hh1, b_ih1, b_hh1, out, ws);

  const unsigned short* H2Fh = (const unsigned short*)(ws + OFF_H2FH);
  const unsigned short* H2Fl = (const unsigned short*)(ws + OFF_H2FL);
  y_proj<<<dim3(TT), dim3(256), 0, stream>>>(H2Fh, H2Fl, w_out, b_out, out);
}

// Round 11
// 9435.356 us; speedup vs baseline: 1.0121x; 1.0121x over previous
//
#include <hip/hip_runtime.h>

// ---------------- problem constants ----------------
#define TT   2048
#define NB   16
#define HH   512
#define NSL  32            // WG slices per layer
#define HSL  16            // hidden units per slice
#define KW   128           // K-range per wave
#define Y_SZ (NB*TT*32)
#define RING 256
#define RM   255

typedef __attribute__((ext_vector_type(8))) short bf16x8;
typedef __attribute__((ext_vector_type(4))) float f32x4;
typedef __attribute__((ext_vector_type(4))) unsigned u32x4;
typedef unsigned long long ull;

// ---------------- workspace layout (bytes) ----------------
#define OFF_XCCV 0u
#define OFF_MODE 256u
#define OFF_PROG 512u
#define OFF_F1L  4096u
#define FLB      (4u*RING*32u*4u)
#define OFF_F1X  (OFF_F1L + FLB)
#define OFF_F2L  (OFF_F1X + FLB)
#define OFF_F2X  (OFF_F2L + FLB)
#define OFF_ZEND (OFF_F2X + FLB)
#define RSLOT    ((size_t)NB*HH)
#define RB       ((size_t)RING*RSLOT*2)
#define OFF_H1LH ((size_t)(1u<<20))
#define OFF_H1LL (OFF_H1LH + RB)
#define OFF_H1XH (OFF_H1LL + RB)
#define OFF_H1XL (OFF_H1XH + RB)
#define OFF_H2LH (OFF_H1XL + RB)
#define OFF_H2LL (OFF_H2LH + RB)
#define OFF_H2XH (OFF_H2LL + RB)
#define OFF_H2XL (OFF_H2XH + RB)
#define FB       ((size_t)TT*RSLOT*2)
#define OFF_H2FH (OFF_H2XL + RB)
#define OFF_H2FL (OFF_H2FH + FB)
#define WS_NEED  (OFF_H2FL + FB)

__device__ __forceinline__ unsigned short f2bf(float x){
  unsigned u = __float_as_uint(x);
  return (unsigned short)((u + 0x7FFFu + ((u >> 16) & 1u)) >> 16);
}
__device__ __forceinline__ float bf2f(unsigned short b){
  return __uint_as_float(((unsigned)b) << 16);
}
__device__ __forceinline__ float sigm(float v){ return 1.0f / (1.0f + __expf(-v)); }
__device__ __forceinline__ float tanh_f(float v){
  float a = fabsf(v);
  float e = __expf(-2.0f * a);
  float t = (1.0f - e) / (1.0f + e);
  return v < 0.0f ? -t : t;
}
__device__ __forceinline__ void split8(const float* __restrict__ p, bf16x8& hi, bf16x8& lo){
#pragma unroll
  for (int j = 0; j < 8; ++j){
    float w = p[j];
    unsigned short h = f2bf(w);
    hi[j] = (short)h;
    lo[j] = (short)f2bf(w - bf2f(h));
  }
}
__device__ __forceinline__ bf16x8 mk(ull a, ull b){
  union { ull u[2]; bf16x8 v; } r; r.u[0] = a; r.u[1] = b; return r.v;
}
__device__ __forceinline__ bf16x8 asfrag(u32x4 v){
  union { u32x4 u; bf16x8 b; } r; r.u = v; return r.b;
}
// ---- LIC (agent-scope) primitives ----
__device__ __forceinline__ ull ld64_lic(const ull* p){
  return __hip_atomic_load(p, __ATOMIC_RELAXED, __HIP_MEMORY_SCOPE_AGENT);
}
__device__ __forceinline__ unsigned ld32_lic(const unsigned* p){
  return __hip_atomic_load(p, __ATOMIC_RELAXED, __HIP_MEMORY_SCOPE_AGENT);
}
__device__ __forceinline__ void st64_lic(ull* p, ull v){
  __hip_atomic_store(p, v, __ATOMIC_RELAXED, __HIP_MEMORY_SCOPE_AGENT);
}
__device__ __forceinline__ void st32_lic(unsigned* p, unsigned v){
  __hip_atomic_store(p, v, __ATOMIC_RELAXED, __HIP_MEMORY_SCOPE_AGENT);
}
__device__ __forceinline__ bf16x8 ld_frag_lic(const unsigned short* p){
  return mk(ld64_lic((const ull*)p), ld64_lic((const ull*)p + 1));
}
// ---- XCD-local primitives: sc0 (coherent, L1-bypass) L2-served loads ----
__device__ __forceinline__ unsigned ld32_l2(const unsigned* p){
  unsigned r;
  asm volatile("global_load_dword %0, %1, off sc0\n\t"
               "s_waitcnt vmcnt(0)"
               : "=&v"(r) : "v"(p) : "memory");
  return r;
}
__device__ __forceinline__ void ld8_l2(const void* ph, const void* pl, u32x4* r){
  asm volatile(
    "global_load_dwordx4 %0, %8, off sc0\n\t"
    "global_load_dwordx4 %1, %8, off offset:64 sc0\n\t"
    "global_load_dwordx4 %2, %8, off offset:128 sc0\n\t"
    "global_load_dwordx4 %3, %8, off offset:192 sc0\n\t"
    "global_load_dwordx4 %4, %9, off sc0\n\t"
    "global_load_dwordx4 %5, %9, off offset:64 sc0\n\t"
    "global_load_dwordx4 %6, %9, off offset:128 sc0\n\t"
    "global_load_dwordx4 %7, %9, off offset:192 sc0\n\t"
    "s_waitcnt vmcnt(0)"
    : "=&v"(r[0]),"=&v"(r[1]),"=&v"(r[2]),"=&v"(r[3]),
      "=&v"(r[4]),"=&v"(r[5]),"=&v"(r[6]),"=&v"(r[7])
    : "v"(ph), "v"(pl) : "memory");
}
// batched LIC loads, FULLY WAITED inside the block
__device__ __forceinline__ void ld8_lic(const void* ph, const void* pl, u32x4* r){
  asm volatile(
    "global_load_dwordx4 %0, %8, off sc0 sc1\n\t"
    "global_load_dwordx4 %1, %8, off offset:64 sc0 sc1\n\t"
    "global_load_dwordx4 %2, %8, off offset:128 sc0 sc1\n\t"
    "global_load_dwordx4 %3, %8, off offset:192 sc0 sc1\n\t"
    "global_load_dwordx4 %4, %9, off sc0 sc1\n\t"
    "global_load_dwordx4 %5, %9, off offset:64 sc0 sc1\n\t"
    "global_load_dwordx4 %6, %9, off offset:128 sc0 sc1\n\t"
    "global_load_dwordx4 %7, %9, off offset:192 sc0 sc1\n\t"
    "s_waitcnt vmcnt(0)"
    : "=&v"(r[0]),"=&v"(r[1]),"=&v"(r[2]),"=&v"(r[3]),
      "=&v"(r[4]),"=&v"(r[5]),"=&v"(r[6]),"=&v"(r[7])
    : "v"(ph), "v"(pl) : "memory");
}
// batched LIC loads, ISSUE ONLY (caller merges the vmcnt(0) with store drain)
__device__ __forceinline__ void ld8_lic_issue(const void* ph, const void* pl, u32x4* r){
  asm volatile(
    "global_load_dwordx4 %0, %8, off sc0 sc1\n\t"
    "global_load_dwordx4 %1, %8, off offset:64 sc0 sc1\n\t"
    "global_load_dwordx4 %2, %8, off offset:128 sc0 sc1\n\t"
    "global_load_dwordx4 %3, %8, off offset:192 sc0 sc1\n\t"
    "global_load_dwordx4 %4, %9, off sc0 sc1\n\t"
    "global_load_dwordx4 %5, %9, off offset:64 sc0 sc1\n\t"
    "global_load_dwordx4 %6, %9, off offset:128 sc0 sc1\n\t"
    "global_load_dwordx4 %7, %9, off offset:192 sc0 sc1"
    : "=&v"(r[0]),"=&v"(r[1]),"=&v"(r[2]),"=&v"(r[3]),
      "=&v"(r[4]),"=&v"(r[5]),"=&v"(r[6]),"=&v"(r[7])
    : "v"(ph), "v"(pl) : "memory");
}
__device__ __forceinline__ void st64_pl(void* p, ull v){
  asm volatile("global_store_dwordx2 %0, %1, off" :: "v"(p), "v"(v) : "memory");
}
__device__ __forceinline__ void st32_pl(unsigned* p, unsigned v){
  asm volatile("global_store_dword %0, %1, off" :: "v"(p), "v"(v) : "memory");
}

// ---- waits (octet scope + r17 backoff) ----
// r17: __builtin_amdgcn_s_sleep(1) (~64 cy) after each FAILED poll round.
// 32+ waves spin on the SAME 128B flag line at max rate; the producer's
// flag store must win L2 arbitration against that read storm. Backoff
// cuts poll rate ~10x while adding <=64 cy to detect latency (negligible
// vs the ~11k-cy step period). Timing-only change — cannot affect
// correctness.
__device__ __forceinline__ int wait_hy8(const unsigned* bL, const unsigned* bX,
                                        unsigned expect, int lane, int base, int lmode, long& bud){
  if (!lmode){
    bool ok = (lane >= 8);
    while (__ballot(!ok) != 0ULL){
      if (!ok) ok = (ld32_lic(bX + base + lane) >= expect);
      if (__ballot(!ok) == 0ULL) break;
      __builtin_amdgcn_s_sleep(1);
      if (--bud < 0) return 0;
    }
    return 0;
  }
  bool okL = (lane >= 8);
  int k = 0;
  while (true){
    if (__ballot(!okL) == 0ULL) return 1;
    if (!okL) okL = (ld32_l2(bL + base + lane) >= expect);
    if ((++k & 15) == 0){
      bool okX = (lane >= 8);
      if (!okX) okX = (ld32_lic(bX + base + lane) >= expect);
      if (__ballot(!okX) == 0ULL){
        if (!okL) okL = (ld32_l2(bL + base + lane) >= expect);
        return (__ballot(!okL) == 0ULL) ? 1 : 0;
      }
    }
    if (__ballot(!okL) != 0ULL) __builtin_amdgcn_s_sleep(1);
    if (--bud < 0) return 0;
  }
}
// LIC-only value wait, octet scope, with backoff
__device__ __forceinline__ void wait_lic8(const unsigned* bX, unsigned expect, int lane, int base, long& bud){
  bool ok = (lane >= 8);
  while (__ballot(!ok) != 0ULL){
    if (!ok) ok = (ld32_lic(bX + base + lane) >= expect);
    if (__ballot(!ok) == 0ULL) break;
    __builtin_amdgcn_s_sleep(1);
    if (--bud < 0) return;
  }
}

// =====================================================================
// Persistent 2-layer LSTM — r17: r13 (passing baseline) + s_sleep(1)
// poll backoff. The layer-1 tail region is CLOSED: r10/r12/r14/r16 all
// corrupted identically under any tail re-timing or added loop-carried
// state (incl. r16's fused-asm variant, which falsified the VGPR-hazard
// theory); r13's exact tail is the only known-good form. This round's
// single delta is timing-only (backoff in the spin loops) and tests the
// flag-line-contention theory.
// History: r6 baseline 10084 -> r11 sc0-loads 9450 (buffer_inv removal,
// the one confirmed win) -> r13 octet waits ~neutral.
// =====================================================================
__global__ __launch_bounds__(256, 1) void lstm_persist(
    const float* __restrict__ x,
    const float* __restrict__ w_ih0, const float* __restrict__ w_hh0,
    const float* __restrict__ b_ih0, const float* __restrict__ b_hh0,
    const float* __restrict__ w_ih1, const float* __restrict__ w_hh1,
    const float* __restrict__ b_ih1, const float* __restrict__ b_hh1,
    float* __restrict__ out, unsigned char* __restrict__ ws)
{
  unsigned* XCCV = (unsigned*)(ws + OFF_XCCV);
  unsigned* MODE = (unsigned*)(ws + OFF_MODE);
  unsigned* PROG = (unsigned*)(ws + OFF_PROG);
  unsigned* F1L  = (unsigned*)(ws + OFF_F1L);
  unsigned* F1X  = (unsigned*)(ws + OFF_F1X);
  unsigned* F2L  = (unsigned*)(ws + OFF_F2L);
  unsigned* F2X  = (unsigned*)(ws + OFF_F2X);
  unsigned short* H1Lh = (unsigned short*)(ws + OFF_H1LH);
  unsigned short* H1Ll = (unsigned short*)(ws + OFF_H1LL);
  unsigned short* H1Xh = (unsigned short*)(ws + OFF_H1XH);
  unsigned short* H1Xl = (unsigned short*)(ws + OFF_H1XL);
  unsigned short* H2Lh = (unsigned short*)(ws + OFF_H2LH);
  unsigned short* H2Ll = (unsigned short*)(ws + OFF_H2LL);
  unsigned short* H2Xh = (unsigned short*)(ws + OFF_H2XH);
  unsigned short* H2Xl = (unsigned short*)(ws + OFF_H2XL);
  unsigned short* H2Fh = (unsigned short*)(ws + OFF_H2FH);
  unsigned short* H2Fl = (unsigned short*)(ws + OFF_H2FL);

  const int tid  = threadIdx.x;
  const int lane = tid & 63;
  const int wv   = tid >> 6;
  const int m16  = lane & 15;
  const int quad = lane >> 4;

  const int bid = blockIdx.x;
  const int xs  = bid & 7;
  const int pos = bid >> 3;
  if (xs >= 2 || pos >= NSL) return;
  const int layer = xs;
  const int sl    = pos;
  const int role  = layer * NSL + sl;
  const int j0    = sl * HSL;
  const int kwb   = wv * KW;
  const int fb8   = wv * 8;            // octet flag base (this wave's producers)

  long bud = 3000000;

  // ---- placement verification (r6) ----
  if (tid == 0){
    unsigned xcc = 0xDEAD;
    asm volatile("s_getreg_b32 %0, hwreg(HW_REG_XCC_ID)" : "=s"(xcc));
    st32_lic(XCCV + role, (xcc & 255u) | 0x100u);
  }
  __syncthreads();
  if (bid == 0 && wv == 0){
    bool got = false; unsigned v = 0;
    long b2 = 2000000;
    while (true){
      if (!got){ v = ld32_lic(XCCV + lane); got = (v & 0x100u) != 0u; }
      if (__ballot(!got) == 0ULL) break;
      if (--b2 < 0) break;
    }
    unsigned v0  = (unsigned)__shfl((int)v, 0, 64);
    unsigned v32 = (unsigned)__shfl((int)v, 32, 64);
    bool ok = got && ((lane < 32) ? (v == v0) : (v == v32));
    unsigned mode = (__ballot(!ok) == 0ULL) ? 1u : 0u;
    if (lane == 0) st32_lic(MODE, mode | 0x100u);
  }
  __shared__ unsigned s_mode;
  if (tid == 0){
    unsigned m = 0; long b3 = 2000000;
    do { m = ld32_lic(MODE); } while (!(m & 0x100u) && --b3 > 0);
    s_mode = m;
  }
  __syncthreads();
  int lmode = ((s_mode & 0x100u) && (s_mode & 1u)) ? 1 : 0;

  const float* Wh  = layer ? w_hh1 : w_hh0;
  const float* biL = layer ? b_ih1 : b_ih0;
  const float* bhL = layer ? b_hh1 : b_hh0;

  bf16x8 Bh_hi[4][4], Bh_lo[4][4];
#pragma unroll
  for (int g = 0; g < 4; ++g)
#pragma unroll
    for (int c = 0; c < 4; ++c){
      int row = g*HH + j0 + m16;
      int k0  = kwb + c*32 + quad*8;
      split8(Wh + (size_t)row*HH + k0, Bh_hi[g][c], Bh_lo[g][c]);
    }
  bf16x8 Bi_hi[4][4], Bi_lo[4][4];
  if (layer){
#pragma unroll
    for (int g = 0; g < 4; ++g)
#pragma unroll
      for (int c = 0; c < 4; ++c){
        int row = g*HH + j0 + m16;
        int k0  = kwb + c*32 + quad*8;
        split8(w_ih1 + (size_t)row*HH + k0, Bi_hi[g][c], Bi_lo[g][c]);
      }
  } else if (wv == 0){
#pragma unroll
    for (int g = 0; g < 4; ++g){
      int row = g*HH + j0 + m16;
      split8(w_ih0 + (size_t)row*32 + quad*8, Bi_hi[g][0], Bi_lo[g][0]);
    }
  }

  const int eb = tid >> 4;
  const int ej = tid & 15;
  float bias[4];
#pragma unroll
  for (int g = 0; g < 4; ++g){
    int r = g*HH + j0 + ej;
    bias[g] = biL[r] + bhL[r];
  }

  float cst = 0.0f;
  __shared__ float P[4][4][16][16];   // unpadded: reads 2 lanes/bank = free
  unsigned minp = 0;
  unsigned f1seen = 0;                // highest verified F1X value (layer1 tail batching)

  // ---- layer1 preamble: input matmul for step 0 (h1(0) = H1X slot 1) ----
  f32x4 accIn[4];
#pragma unroll
  for (int g = 0; g < 4; ++g) accIn[g] = f32x4{0.f, 0.f, 0.f, 0.f};
  if (layer){
    wait_lic8(F1X + ((size_t)wv*RING + 1)*32, 1u, lane, fb8, bud);
    f1seen = 1u;
    const size_t ib = ((size_t)1*NB + m16)*HH + kwb + quad*8;
    u32x4 r[8];
    ld8_lic(H1Xh + ib, H1Xl + ib, r);
#pragma unroll
    for (int c = 0; c < 4; ++c){
      bf16x8 ah = asfrag(r[c]);
      bf16x8 al = asfrag(r[4+c]);
#pragma unroll
      for (int g = 0; g < 4; ++g){
        accIn[g] = __builtin_amdgcn_mfma_f32_16x16x32_bf16(ah, Bi_hi[g][c], accIn[g], 0, 0, 0);
        accIn[g] = __builtin_amdgcn_mfma_f32_16x16x32_bf16(al, Bi_hi[g][c], accIn[g], 0, 0, 0);
        accIn[g] = __builtin_amdgcn_mfma_f32_16x16x32_bf16(ah, Bi_lo[g][c], accIn[g], 0, 0, 0);
      }
    }
  }

  for (int t = 0; t < TT; ++t){
    const unsigned srec = (unsigned)t & RM;
    const unsigned spub = (unsigned)(t+1) & RM;
    f32x4 acc[4];

    if (layer == 0){
#pragma unroll
      for (int g = 0; g < 4; ++g) acc[g] = f32x4{0.f, 0.f, 0.f, 0.f};
      if (wv == 0){                        // x-term overlaps waits
        const float* xp = x + ((size_t)m16*TT + t)*32 + quad*8;
        bf16x8 ah, al;
#pragma unroll
        for (int j = 0; j < 8; ++j){
          float v = xp[j];
          unsigned short h = f2bf(v);
          ah[j] = (short)h;
          al[j] = (short)f2bf(v - bf2f(h));
        }
#pragma unroll
        for (int g = 0; g < 4; ++g){
          acc[g] = __builtin_amdgcn_mfma_f32_16x16x32_bf16(ah, Bi_hi[g][0], acc[g], 0, 0, 0);
          acc[g] = __builtin_amdgcn_mfma_f32_16x16x32_bf16(al, Bi_hi[g][0], acc[g], 0, 0, 0);
          acc[g] = __builtin_amdgcn_mfma_f32_16x16x32_bf16(ah, Bi_lo[g][0], acc[g], 0, 0, 0);
        }
      }
      while ((long)(t+1) - (long)minp > 248L){          // ring backpressure
        unsigned v = (lane < 32) ? ld32_lic(PROG + lane) : 0xFFFFFFFFu;
        unsigned m = v;
#pragma unroll
        for (int o = 1; o < 32; o <<= 1){
          unsigned ov = (unsigned)__shfl_xor((int)m, o, 32);
          m = m < ov ? m : ov;
        }
        minp = (unsigned)__shfl((int)m, 0, 64);
        if ((long)(t+1) - (long)minp > 248L) __builtin_amdgcn_s_sleep(1);
        if (--bud < 0) break;
      }
      int got = lmode;
      if (t > 0){
        got = wait_hy8(F1L + ((size_t)wv*RING + srec)*32,
                       F1X + ((size_t)wv*RING + srec)*32, (unsigned)t, lane, fb8, lmode, bud);
        if (!got) lmode = 0;
      }
      const size_t rb = ((size_t)srec*NB + m16)*HH + kwb + quad*8;
      u32x4 r[8];
      if (got) ld8_l2(H1Lh + rb, H1Ll + rb, r);
      else {
#pragma unroll
        for (int c = 0; c < 4; ++c){
          r[c]   = (u32x4)__builtin_bit_cast(u32x4, ld_frag_lic(H1Xh + rb + c*32));
          r[4+c] = (u32x4)__builtin_bit_cast(u32x4, ld_frag_lic(H1Xl + rb + c*32));
        }
      }
#pragma unroll
      for (int c = 0; c < 4; ++c){
        bf16x8 ah = asfrag(r[c]);
        bf16x8 al = asfrag(r[4+c]);
#pragma unroll
        for (int g = 0; g < 4; ++g){
          acc[g] = __builtin_amdgcn_mfma_f32_16x16x32_bf16(ah, Bh_hi[g][c], acc[g], 0, 0, 0);
          acc[g] = __builtin_amdgcn_mfma_f32_16x16x32_bf16(al, Bh_hi[g][c], acc[g], 0, 0, 0);
          acc[g] = __builtin_amdgcn_mfma_f32_16x16x32_bf16(ah, Bh_lo[g][c], acc[g], 0, 0, 0);
        }
      }
    } else {
      // acc starts from the pipelined input matmul (h1(t) @ W_ih1^T)
#pragma unroll
      for (int g = 0; g < 4; ++g) acc[g] = accIn[g];
      int got = lmode;
      if (t > 0){
        got = wait_hy8(F2L + ((size_t)wv*RING + srec)*32,
                       F2X + ((size_t)wv*RING + srec)*32, (unsigned)t, lane, fb8, lmode, bud);
        if (!got) lmode = 0;
      }
      const size_t rb = ((size_t)srec*NB + m16)*HH + kwb + quad*8;
      u32x4 r[8];
      if (got) ld8_l2(H2Lh + rb, H2Ll + rb, r);
      else {
#pragma unroll
        for (int c = 0; c < 4; ++c){
          r[c]   = (u32x4)__builtin_bit_cast(u32x4, ld_frag_lic(H2Xh + rb + c*32));
          r[4+c] = (u32x4)__builtin_bit_cast(u32x4, ld_frag_lic(H2Xl + rb + c*32));
        }
      }
#pragma unroll
      for (int c = 0; c < 4; ++c){
        bf16x8 ah = asfrag(r[c]);
        bf16x8 al = asfrag(r[4+c]);
#pragma unroll
        for (int g = 0; g < 4; ++g){
          acc[g] = __builtin_amdgcn_mfma_f32_16x16x32_bf16(ah, Bh_hi[g][c], acc[g], 0, 0, 0);
          acc[g] = __builtin_amdgcn_mfma_f32_16x16x32_bf16(al, Bh_hi[g][c], acc[g], 0, 0, 0);
          acc[g] = __builtin_amdgcn_mfma_f32_16x16x32_bf16(ah, Bh_lo[g][c], acc[g], 0, 0, 0);
        }
      }
    }

    // ---- K-reduction via LDS ----
#pragma unroll
    for (int g = 0; g < 4; ++g)
#pragma unroll
      for (int r = 0; r < 4; ++r)
        P[wv][g][quad*4 + r][m16] = acc[g][r];
    __syncthreads();                                   // barrier A

    float G[4];
#pragma unroll
    for (int g = 0; g < 4; ++g)
      G[g] = P[0][g][eb][ej] + P[1][g][eb][ej] + P[2][g][eb][ej] + P[3][g][eb][ej] + bias[g];

    float gi = sigm(G[0]);
    float gf = sigm(G[1]);
    float gc = tanh_f(G[2]);
    float go = sigm(G[3]);
    cst = gf*cst + gi*gc;
    float h = go * tanh_f(cst);

    if (t == TT-1){
      size_t o = (size_t)layer*NB*HH + (size_t)eb*HH + (j0 + ej);
      out[Y_SZ + o] = h;
      out[Y_SZ + 2*NB*HH + o] = cst;
    }

    // ---- dual publish: plain (XCD L2) first, agent (LIC) second ----
    unsigned short hhi = f2bf(h);
    unsigned short hlo = f2bf(h - bf2f(hhi));
    ull h1s = (ull)(unsigned short)__shfl_down((int)hhi, 1, 64);
    ull h2s = (ull)(unsigned short)__shfl_down((int)hhi, 2, 64);
    ull h3s = (ull)(unsigned short)__shfl_down((int)hhi, 3, 64);
    ull l1s = (ull)(unsigned short)__shfl_down((int)hlo, 1, 64);
    ull l2s = (ull)(unsigned short)__shfl_down((int)hlo, 2, 64);
    ull l3s = (ull)(unsigned short)__shfl_down((int)hlo, 3, 64);
    if ((ej & 3) == 0){
      ull vh = (ull)hhi | (h1s << 16) | (h2s << 32) | (h3s << 48);
      ull vl = (ull)hlo | (l1s << 16) | (l2s << 32) | (l3s << 48);
      size_t pr = (((size_t)spub*NB + eb)*HH + (unsigned)(j0 + ej)) >> 2;
      if (layer == 0){
        st64_pl((ull*)H1Lh + pr, vh);
        st64_pl((ull*)H1Ll + pr, vl);
        st64_lic((ull*)H1Xh + pr, vh);
        st64_lic((ull*)H1Xl + pr, vl);
      } else {
        size_t pf_ = (((size_t)t*NB + eb)*HH + (unsigned)(j0 + ej)) >> 2;
        st64_pl((ull*)H2Lh + pr, vh);
        st64_pl((ull*)H2Ll + pr, vl);
        st64_pl((ull*)H2Fh + pf_, vh);
        st64_pl((ull*)H2Fl + pf_, vl);
        st64_lic((ull*)H2Xh + pr, vh);
        st64_lic((ull*)H2Xl + pr, vl);
      }
    }

    if (layer == 0){
      // certify ONLY the plain H1L stores (in-order vmcnt retire: they are
      // the oldest), publish L flags, then pay the LIC ack off the
      // consumers' detect path.
      asm volatile("s_waitcnt vmcnt(2) lgkmcnt(0)" ::: "memory");
      __builtin_amdgcn_s_barrier();                    // barrier B (raw)
      if (tid == 0){
        unsigned val = (unsigned)(t+1);
#pragma unroll
        for (int r2 = 0; r2 < 4; ++r2)
          st32_pl(F1L + ((size_t)r2*RING + spub)*32 + sl, val);
      }
      asm volatile("s_waitcnt vmcnt(0)" ::: "memory"); // certify agent stores
      __builtin_amdgcn_s_barrier();                    // barrier C (raw)
      if (tid == 0){
        unsigned val = (unsigned)(t+1);
#pragma unroll
        for (int r2 = 0; r2 < 4; ++r2)
          st32_lic(F1X + ((size_t)r2*RING + spub)*32 + sl, val);
      }
    } else {
      // certify ONLY the plain H2L stores (oldest 2 of the 6; at t==TT-1
      // the out[] stores precede and vmcnt(4) still retires past H2L).
      asm volatile("s_waitcnt vmcnt(4) lgkmcnt(0)" ::: "memory");
      __builtin_amdgcn_s_barrier();                    // barrier B (raw)
      if (tid == 0){
        unsigned val = (unsigned)(t+1);
#pragma unroll
        for (int r2 = 0; r2 < 4; ++r2)
          st32_pl(F2L + ((size_t)r2*RING + spub)*32 + sl, val);
      }
      if (t + 1 < TT){
        // ---- tail: h1 prefetch overlapped with the LIC store drain ----
        // (r13 form verbatim — this region is closed to modification)
        if (f1seen < (unsigned)(t+2)){                 // batched flag check
          unsigned tgt = (unsigned)(t + 17);
          if (tgt > (unsigned)TT) tgt = (unsigned)TT;
          wait_lic8(F1X + ((size_t)wv*RING + (tgt & RM))*32, tgt, lane, fb8, bud);
          f1seen = tgt;
        }
        const unsigned nslot = (unsigned)(t+2) & RM;
        const size_t nb_ = ((size_t)nslot*NB + m16)*HH + kwb + quad*8;
        u32x4 rr[8];
        ld8_lic_issue(H1Xh + nb_, H1Xl + nb_, rr);
        // one drain window: H2F/H2X store acks + the 8 LIC loads together
        asm volatile("s_waitcnt vmcnt(0)" ::: "memory");
        __builtin_amdgcn_sched_barrier(0);
        __builtin_amdgcn_s_barrier();                  // barrier C (raw)
        if (tid == 0){
          unsigned val = (unsigned)(t+1);
#pragma unroll
          for (int r2 = 0; r2 < 4; ++r2)
            st32_lic(F2X + ((size_t)r2*RING + spub)*32 + sl, val);
          st32_lic(PROG + sl, val);
        }
#pragma unroll
        for (int g = 0; g < 4; ++g) accIn[g] = f32x4{0.f, 0.f, 0.f, 0.f};
#pragma unroll
        for (int c = 0; c < 4; ++c){
          bf16x8 ah = asfrag(rr[c]);
          bf16x8 al = asfrag(rr[4+c]);
#pragma unroll
          for (int g = 0; g < 4; ++g){
            accIn[g] = __builtin_amdgcn_mfma_f32_16x16x32_bf16(ah, Bi_hi[g][c], accIn[g], 0, 0, 0);
            accIn[g] = __builtin_amdgcn_mfma_f32_16x16x32_bf16(al, Bi_hi[g][c], accIn[g], 0, 0, 0);
            accIn[g] = __builtin_amdgcn_mfma_f32_16x16x32_bf16(ah, Bi_lo[g][c], accIn[g], 0, 0, 0);
          }
        }
      }
      // t == TT-1: F2X(TT)/PROG(TT) have no consumer — skip; kernel-end
      // completion drains the remaining stores.
    }
  }
}

// =====================================================================
// y = h2 @ w_out^T + b_out   (parallel epilogue, one block per timestep)
// =====================================================================
__global__ __launch_bounds__(256, 1) void y_proj(
    const unsigned short* __restrict__ Hhi2, const unsigned short* __restrict__ Hlo2,
    const float* __restrict__ w_out, const float* __restrict__ b_out,
    float* __restrict__ out)
{
  __shared__ float hsh[NB][HH + 1];
  __shared__ float wsh[32][HH + 1];
  const int tid = threadIdx.x;
  const int t = blockIdx.x;

  for (int i = tid; i < 32*HH; i += 256){
    int o = i >> 9, k = i & (HH-1);
    wsh[o][k] = w_out[i];
  }
  for (int i = tid; i < NB*HH; i += 256){
    int b = i >> 9, k = i & (HH-1);
    size_t off = ((size_t)t*NB + b)*HH + k;
    hsh[b][k] = bf2f(Hhi2[off]) + bf2f(Hlo2[off]);
  }
  __syncthreads();

  const int o = tid & 31, bg = tid >> 5;
  float a0 = 0.f, a1 = 0.f;
  for (int k = 0; k < HH; ++k){
    float w = wsh[o][k];
    a0 += w * hsh[bg][k];
    a1 += w * hsh[bg + 8][k];
  }
  float bo = b_out[o];
  out[((size_t)bg*TT + t)*32 + o] = a0 + bo;
  out[((size_t)(bg+8)*TT + t)*32 + o] = a1 + bo;
}

extern "C" void kernel_launch(void* const* d_in, const int* in_sizes, int n_in,
                              void* d_out, int out_size, void* d_ws, size_t ws_size,
                              hipStream_t stream)
{
  (void)in_sizes; (void)n_in; (void)out_size;
  const float* x     = (const float*)d_in[0];
  const float* w_ih0 = (const float*)d_in[1];
  const float* w_hh0 = (const float*)d_in[2];
  const float* b_ih0 = (const float*)d_in[3];
  const float* b_hh0 = (const float*)d_in[4];
  const float* w_ih1 = (const float*)d_in[5];
  const float* w_hh1 = (const float*)d_in[6];
  const float* b_ih1 = (const float*)d_in[7];
  const float* b_hh1 = (const float*)d_in[8];
  const float* w_out = (const float*)d_in[9];
  const float* b_out = (const float*)d_in[10];
  float* out = (float*)d_out;
  unsigned char* ws = (unsigned char*)d_ws;

  if (ws_size < WS_NEED) return;

  hipMemsetAsync(ws, 0, OFF_ZEND, stream);
  hipMemsetAsync(ws + OFF_H1LH, 0, RSLOT*2, stream);
  hipMemsetAsync(ws + OFF_H1LL, 0, RSLOT*2, stream);
  hipMemsetAsync(ws + OFF_H1XH, 0, RSLOT*2, stream);
  hipMemsetAsync(ws + OFF_H1XL, 0, RSLOT*2, stream);
  hipMemsetAsync(ws + OFF_H2LH, 0, RSLOT*2, stream);
  hipMemsetAsync(ws + OFF_H2LL, 0, RSLOT*2, stream);
  hipMemsetAsync(ws + OFF_H2XH, 0, RSLOT*2, stream);
  hipMemsetAsync(ws + OFF_H2XL, 0, RSLOT*2, stream);

  lstm_persist<<<dim3(512), dim3(256), 0, stream>>>(
      x, w_ih0, w_hh0, b_ih0, b_hh0, w_ih1, w_hh1, b_ih1, b_hh1, out, ws);

  const unsigned short* H2Fh = (const unsigned short*)(ws + OFF_H2FH);
  const unsigned short* H2Fl = (const unsigned short*)(ws + OFF_H2FL);
  y_proj<<<dim3(TT), dim3(256), 0, stream>>>(H2Fh, H2Fl, w_out, b_out, out);
}